// Round 19
// baseline (133.835 us; speedup 1.0000x reference)
//
#include <hip/hip_runtime.h>
#include <hip/hip_bf16.h>

#define TOPK 10
#define LN_EPS 1e-5f
#define NROWS 4096
#define VDIM 50257
#define PADV 50432     // VDIM padded to 256 (197 tiles)
#define NTILES 197
#define TBLK 788       // transpose blocks (197 c-tiles x 4 k-groups)
#define CBLK 2048      // collect MFMA-role blocks
#define XPAD 20        // xsT row pad (floats)
// old (fallback) path
#define NC 13
#define TV 4096
#define BM 32
// new path
#define NSEG 32        // tile segments (6-7 tiles each)
#define CAP 192        // per-row candidate buffer slots
#define LCAP 16        // per-(row,block) LDS staging slots (P(overflow) ~ 1e-10)
#define ALPHA 3.0f     // tau = ALPHA * sigma_w * ||x||_2  (E[collect] ~ 68/row)
#define DELTA_C 2.5e-4f // strict margin per ||x||_1 >= 2*eps_bf16

typedef __bf16 bf16x8 __attribute__((ext_vector_type(8)));
typedef float f32x16 __attribute__((ext_vector_type(16)));

__device__ __forceinline__ bool tk_better(float v1, int i1, float v2, int i2) {
    return v1 > v2 || (v1 == v2 && i1 < i2);
}

// sum the 8 cacheline-spaced gw2 partial slots — IDENTICAL order in collect and final
__device__ __forceinline__ float gw2_sum(const float* __restrict__ gw2s) {
    float g = 0.f;
    #pragma unroll
    for (int i = 0; i < 8; ++i) g += gw2s[i*32];
    return g;
}

template<int K>
__device__ __forceinline__ void tk_insertT(float v, int ix, float (&tv)[K], int (&tix)[K]) {
    if (!tk_better(v, ix, tv[K-1], tix[K-1])) return;
    #pragma unroll
    for (int q = K - 1; q > 0; --q) {
        bool bqm1 = tk_better(v, ix, tv[q-1], tix[q-1]);
        bool bq   = tk_better(v, ix, tv[q],   tix[q]);
        float nv = bqm1 ? tv[q-1] : (bq ? v : tv[q]);
        int   ni = bqm1 ? tix[q-1] : (bq ? ix : tix[q]);
        tv[q] = nv; tix[q] = ni;
    }
    if (tk_better(v, ix, tv[0], tix[0])) { tv[0] = v; tix[0] = ix; }
}

// ---------------- Kernel T: WvTb transpose + gw2 partials ----------------
// r36 win: per-block LDS reduce -> ONE atomic per block into 8 cacheline-spaced slots
// (the old single-cacheline gw2 atomic was a ~65us chip-wide serializer).
__global__ __launch_bounds__(256) void transpose_kernel(
    const float* __restrict__ Wv, __bf16* __restrict__ WvTb,
    float* __restrict__ gw2s)
{
    __shared__ float t[32*260];
    __shared__ float gpart[4];
    const int c0 = (blockIdx.x % 197) * 256;
    const int k0 = (blockIdx.x / 197) * 32;
    const int tid = threadIdx.x;
    const int j = tid >> 3;
    #pragma unroll
    for (int m = 0; m < 8; ++m) {
        int c = (tid & 7)*4 + m*32;
        int col = c0 + c;
        float4 v;
        if (col + 3 < VDIM) v = *(const float4*)(Wv + (size_t)(k0 + j)*VDIM + col);
        else {
            float tmp[4];
            #pragma unroll
            for (int q = 0; q < 4; ++q) tmp[q] = (col + q < VDIM) ? Wv[(size_t)(k0+j)*VDIM + col + q] : 0.f;
            v = make_float4(tmp[0], tmp[1], tmp[2], tmp[3]);
        }
        *(float4*)(t + j*260 + c) = v;
    }
    __syncthreads();
    const int col = c0 + tid;
    // plane-major bf16 (pads zero-filled)
    const int tile = c0 >> 8;
    #pragma unroll
    for (int jg = 0; jg < 4; ++jg) {
        const int kbase = k0 + jg*8;
        const int ks = kbase >> 4, kh = (kbase >> 3) & 1;
        __bf16 bb[8];
        if (col < VDIM) {
            #pragma unroll
            for (int i = 0; i < 8; ++i) bb[i] = (__bf16)t[(jg*8 + i)*260 + tid];
        } else {
            #pragma unroll
            for (int i = 0; i < 8; ++i) bb[i] = (__bf16)0.f;
        }
        *(uint4*)(WvTb + (size_t)tile*32768 + (size_t)(ks*2 + kh)*2048 + (size_t)tid*8) = *(uint4*)bb;
    }
    float p = 0.f;
    if (col < VDIM) {
        #pragma unroll
        for (int i = 0; i < 32; ++i) { float v = t[i*260 + tid]; p = fmaf(v, v, p); }
    }
    #pragma unroll
    for (int m = 1; m < 64; m <<= 1) p += __shfl_xor(p, m);
    if ((tid & 63) == 0) gpart[tid >> 6] = p;
    __syncthreads();
    if (tid == 0)
        atomicAdd(&gw2s[(blockIdx.x & 7) * 32],
                  (gpart[0] + gpart[1]) + (gpart[2] + gpart[3]));
}

// ---------------- Kernel M: mlp, 16 rows/block, 4-row register reuse ----------------
__global__ __launch_bounds__(512) void mlp16_kernel(
    const float* __restrict__ psi,
    const float* __restrict__ W0, const float* __restrict__ b0, const float* __restrict__ g0, const float* __restrict__ be0,
    const float* __restrict__ W1, const float* __restrict__ b1, const float* __restrict__ g1, const float* __restrict__ be1,
    const float* __restrict__ W2, const float* __restrict__ b2, const float* __restrict__ g2, const float* __restrict__ be2,
    float* __restrict__ xf, __bf16* __restrict__ xb,
    float* __restrict__ nrm1, float* __restrict__ nrm2)
{
    __shared__ float wbuf[128*128];         // staged W layer (64 KB)
    __shared__ float xsT[128*XPAD];         // x transposed: [k][16 rows], padded (10 KB)
    __shared__ float4 red1[8], red2[8];
    const int tid  = threadIdx.x;
    const int row0 = blockIdx.x * 16;
    const int q    = tid >> 7;     // row-quad 0..3 (rows 4q..4q+3)
    const int j    = tid & 127;    // output col
    const int w    = tid >> 6;     // wave 0..7
    const int l    = tid & 63;

    // stage W0 (64x128 = 2048 float4) + psi -> xsT
    #pragma unroll
    for (int m = 0; m < 4; ++m) {
        int idx = m*512 + tid;
        *(float4*)(wbuf + idx*4) = *(const float4*)(W0 + idx*4);
    }
    #pragma unroll
    for (int m = 0; m < 2; ++m) {
        int idx = m*512 + tid;         // 0..1023
        int k = idx & 63, r = idx >> 6;
        xsT[k*XPAD + r] = psi[(size_t)(row0 + r)*64 + k];
    }
    __syncthreads();

    float y[4];
    // ---- layer 0 (K=64), stage W1 in the B1->B2 window ----
    {
        float a0 = 0.f, a1 = 0.f, a2 = 0.f, a3 = 0.f;
        #pragma unroll 8
        for (int k = 0; k < 64; ++k) {
            float wv = wbuf[k*128 + j];
            float4 xv = *(const float4*)(xsT + k*XPAD + q*4);
            a0 = fmaf(xv.x, wv, a0); a1 = fmaf(xv.y, wv, a1);
            a2 = fmaf(xv.z, wv, a2); a3 = fmaf(xv.w, wv, a3);
        }
        const float bj = b0[j];
        const float v0 = a0 + bj, v1 = a1 + bj, v2 = a2 + bj, v3 = a3 + bj;
        float s0 = v0, s1 = v1, s2 = v2, s3 = v3;
        #pragma unroll
        for (int m = 1; m < 64; m <<= 1) {
            s0 += __shfl_xor(s0, m); s1 += __shfl_xor(s1, m);
            s2 += __shfl_xor(s2, m); s3 += __shfl_xor(s3, m);
        }
        if (l == 0) red1[w] = make_float4(s0, s1, s2, s3);
        __syncthreads();
        #pragma unroll
        for (int m = 0; m < 8; ++m) {
            int idx = m*512 + tid;
            *(float4*)(wbuf + idx*4) = *(const float4*)(W1 + idx*4);
        }
        float4 ra = red1[2*q], rb = red1[2*q+1];
        const float mu0 = (ra.x + rb.x)*(1.f/128.f), mu1 = (ra.y + rb.y)*(1.f/128.f);
        const float mu2 = (ra.z + rb.z)*(1.f/128.f), mu3 = (ra.w + rb.w)*(1.f/128.f);
        const float d0 = v0-mu0, d1 = v1-mu1, d2 = v2-mu2, d3 = v3-mu3;
        float t0 = d0*d0, t1 = d1*d1, t2 = d2*d2, t3 = d3*d3;
        #pragma unroll
        for (int m = 1; m < 64; m <<= 1) {
            t0 += __shfl_xor(t0, m); t1 += __shfl_xor(t1, m);
            t2 += __shfl_xor(t2, m); t3 += __shfl_xor(t3, m);
        }
        if (l == 0) red2[w] = make_float4(t0, t1, t2, t3);
        __syncthreads();
        float4 va = red2[2*q], vb = red2[2*q+1];
        const float gj = g0[j], bej = be0[j];
        y[0] = fmaxf(d0*rsqrtf((va.x+vb.x)*(1.f/128.f)+LN_EPS)*gj + bej, 0.f);
        y[1] = fmaxf(d1*rsqrtf((va.y+vb.y)*(1.f/128.f)+LN_EPS)*gj + bej, 0.f);
        y[2] = fmaxf(d2*rsqrtf((va.z+vb.z)*(1.f/128.f)+LN_EPS)*gj + bej, 0.f);
        y[3] = fmaxf(d3*rsqrtf((va.w+vb.w)*(1.f/128.f)+LN_EPS)*gj + bej, 0.f);
    }
    #pragma unroll
    for (int i = 0; i < 4; ++i) xsT[j*XPAD + q*4 + i] = y[i];
    __syncthreads();
    // ---- layer 1 (K=128), stage W2 in window ----
    {
        float a0 = 0.f, a1 = 0.f, a2 = 0.f, a3 = 0.f;
        #pragma unroll 8
        for (int k = 0; k < 128; ++k) {
            float wv = wbuf[k*128 + j];
            float4 xv = *(const float4*)(xsT + k*XPAD + q*4);
            a0 = fmaf(xv.x, wv, a0); a1 = fmaf(xv.y, wv, a1);
            a2 = fmaf(xv.z, wv, a2); a3 = fmaf(xv.w, wv, a3);
        }
        const float bj = b1[j];
        const float v0 = a0 + bj, v1 = a1 + bj, v2 = a2 + bj, v3 = a3 + bj;
        float s0 = v0, s1 = v1, s2 = v2, s3 = v3;
        #pragma unroll
        for (int m = 1; m < 64; m <<= 1) {
            s0 += __shfl_xor(s0, m); s1 += __shfl_xor(s1, m);
            s2 += __shfl_xor(s2, m); s3 += __shfl_xor(s3, m);
        }
        if (l == 0) red1[w] = make_float4(s0, s1, s2, s3);
        __syncthreads();
        #pragma unroll
        for (int m = 0; m < 8; ++m) {
            int idx = m*512 + tid;
            *(float4*)(wbuf + idx*4) = *(const float4*)(W2 + idx*4);
        }
        float4 ra = red1[2*q], rb = red1[2*q+1];
        const float mu0 = (ra.x + rb.x)*(1.f/128.f), mu1 = (ra.y + rb.y)*(1.f/128.f);
        const float mu2 = (ra.z + rb.z)*(1.f/128.f), mu3 = (ra.w + rb.w)*(1.f/128.f);
        const float d0 = v0-mu0, d1 = v1-mu1, d2 = v2-mu2, d3 = v3-mu3;
        float t0 = d0*d0, t1 = d1*d1, t2 = d2*d2, t3 = d3*d3;
        #pragma unroll
        for (int m = 1; m < 64; m <<= 1) {
            t0 += __shfl_xor(t0, m); t1 += __shfl_xor(t1, m);
            t2 += __shfl_xor(t2, m); t3 += __shfl_xor(t3, m);
        }
        if (l == 0) red2[w] = make_float4(t0, t1, t2, t3);
        __syncthreads();
        float4 va = red2[2*q], vb = red2[2*q+1];
        const float gj = g1[j], bej = be1[j];
        y[0] = fmaxf(d0*rsqrtf((va.x+vb.x)*(1.f/128.f)+LN_EPS)*gj + bej, 0.f);
        y[1] = fmaxf(d1*rsqrtf((va.y+vb.y)*(1.f/128.f)+LN_EPS)*gj + bej, 0.f);
        y[2] = fmaxf(d2*rsqrtf((va.z+vb.z)*(1.f/128.f)+LN_EPS)*gj + bej, 0.f);
        y[3] = fmaxf(d3*rsqrtf((va.w+vb.w)*(1.f/128.f)+LN_EPS)*gj + bej, 0.f);
    }
    #pragma unroll
    for (int i = 0; i < 4; ++i) xsT[j*XPAD + q*4 + i] = y[i];
    __syncthreads();
    // ---- layer 2 (K=128) ----
    {
        float a0 = 0.f, a1 = 0.f, a2 = 0.f, a3 = 0.f;
        #pragma unroll 8
        for (int k = 0; k < 128; ++k) {
            float wv = wbuf[k*128 + j];
            float4 xv = *(const float4*)(xsT + k*XPAD + q*4);
            a0 = fmaf(xv.x, wv, a0); a1 = fmaf(xv.y, wv, a1);
            a2 = fmaf(xv.z, wv, a2); a3 = fmaf(xv.w, wv, a3);
        }
        const float bj = b2[j];
        const float v0 = a0 + bj, v1 = a1 + bj, v2 = a2 + bj, v3 = a3 + bj;
        float s0 = v0, s1 = v1, s2 = v2, s3 = v3;
        #pragma unroll
        for (int m = 1; m < 64; m <<= 1) {
            s0 += __shfl_xor(s0, m); s1 += __shfl_xor(s1, m);
            s2 += __shfl_xor(s2, m); s3 += __shfl_xor(s3, m);
        }
        if (l == 0) red1[w] = make_float4(s0, s1, s2, s3);
        __syncthreads();
        float4 ra = red1[2*q], rb = red1[2*q+1];
        const float mu0 = (ra.x + rb.x)*(1.f/128.f), mu1 = (ra.y + rb.y)*(1.f/128.f);
        const float mu2 = (ra.z + rb.z)*(1.f/128.f), mu3 = (ra.w + rb.w)*(1.f/128.f);
        const float d0 = v0-mu0, d1 = v1-mu1, d2 = v2-mu2, d3 = v3-mu3;
        float t0 = d0*d0, t1 = d1*d1, t2 = d2*d2, t3 = d3*d3;
        #pragma unroll
        for (int m = 1; m < 64; m <<= 1) {
            t0 += __shfl_xor(t0, m); t1 += __shfl_xor(t1, m);
            t2 += __shfl_xor(t2, m); t3 += __shfl_xor(t3, m);
        }
        if (l == 0) red2[w] = make_float4(t0, t1, t2, t3);
        __syncthreads();
        float4 va = red2[2*q], vb = red2[2*q+1];
        const float gj = g2[j], bej = be2[j];
        y[0] = fmaxf(d0*rsqrtf((va.x+vb.x)*(1.f/128.f)+LN_EPS)*gj + bej, 0.f);
        y[1] = fmaxf(d1*rsqrtf((va.y+vb.y)*(1.f/128.f)+LN_EPS)*gj + bej, 0.f);
        y[2] = fmaxf(d2*rsqrtf((va.z+vb.z)*(1.f/128.f)+LN_EPS)*gj + bej, 0.f);
        y[3] = fmaxf(d3*rsqrtf((va.w+vb.w)*(1.f/128.f)+LN_EPS)*gj + bej, 0.f);
    }

    // outputs (coalesced across j)
    #pragma unroll
    for (int i = 0; i < 4; ++i) {
        const int rr = row0 + q*4 + i;
        xf[(size_t)rr*128 + j] = y[i];
        xb[(size_t)rr*128 + j] = (__bf16)y[i];
    }
    // ||x||_1, ||x||_2^2 per row (y >= 0 post-ReLU)
    {
        float s0 = y[0], s1 = y[1], s2 = y[2], s3 = y[3];
        #pragma unroll
        for (int m = 1; m < 64; m <<= 1) {
            s0 += __shfl_xor(s0, m); s1 += __shfl_xor(s1, m);
            s2 += __shfl_xor(s2, m); s3 += __shfl_xor(s3, m);
        }
        if (l == 0) red1[w] = make_float4(s0, s1, s2, s3);
        float t0 = y[0]*y[0], t1 = y[1]*y[1], t2 = y[2]*y[2], t3 = y[3]*y[3];
        #pragma unroll
        for (int m = 1; m < 64; m <<= 1) {
            t0 += __shfl_xor(t0, m); t1 += __shfl_xor(t1, m);
            t2 += __shfl_xor(t2, m); t3 += __shfl_xor(t3, m);
        }
        if (l == 0) red2[w] = make_float4(t0, t1, t2, t3);
        __syncthreads();
        if (j == 0) {    // one thread per row-quad
            float4 ra = red1[2*q], rb = red1[2*q+1];
            float4 va = red2[2*q], vb = red2[2*q+1];
            nrm1[row0 + q*4 + 0] = ra.x + rb.x;
            nrm1[row0 + q*4 + 1] = ra.y + rb.y;
            nrm1[row0 + q*4 + 2] = ra.z + rb.z;
            nrm1[row0 + q*4 + 3] = ra.w + rb.w;
            nrm2[row0 + q*4 + 0] = va.x + vb.x;
            nrm2[row0 + q*4 + 1] = va.y + vb.y;
            nrm2[row0 + q*4 + 2] = va.z + vb.z;
            nrm2[row0 + q*4 + 3] = va.w + vb.w;
        }
    }
}

// ---------------- fallback-path mlp (old structure) ----------------
template<int KD>
__device__ __forceinline__ float mlp_layer_fb(const float* xs, float* red, const float* __restrict__ W,
                                              const float* __restrict__ b, const float* __restrict__ g,
                                              const float* __restrict__ be, int j, int wid, int lane) {
    float acc = b[j];
    #pragma unroll 8
    for (int k = 0; k < KD; ++k) acc = fmaf(xs[k], W[k*128 + j], acc);
    float s = acc;
    #pragma unroll
    for (int m = 1; m < 64; m <<= 1) s += __shfl_xor(s, m);
    if (lane == 0) red[wid] = s;
    __syncthreads();
    float mu = (red[0] + red[1]) * (1.f/128.f);
    float d = acc - mu;
    s = d * d;
    #pragma unroll
    for (int m = 1; m < 64; m <<= 1) s += __shfl_xor(s, m);
    __syncthreads();
    if (lane == 0) red[wid] = s;
    __syncthreads();
    float var = (red[0] + red[1]) * (1.f/128.f);
    float y = d * rsqrtf(var + LN_EPS) * g[j] + be[j];
    return fmaxf(y, 0.f);
}

__global__ __launch_bounds__(512) void mlp_kernel(
    const float* __restrict__ psi,
    const float* __restrict__ W0, const float* __restrict__ b0, const float* __restrict__ g0, const float* __restrict__ be0,
    const float* __restrict__ W1, const float* __restrict__ b1, const float* __restrict__ g1, const float* __restrict__ be1,
    const float* __restrict__ W2, const float* __restrict__ b2, const float* __restrict__ g2, const float* __restrict__ be2,
    float* __restrict__ xf)
{
    __shared__ float xs[4][128];
    __shared__ float red[4][2];
    const int gi = threadIdx.x >> 7;    // row group 0..3
    const int j  = threadIdx.x & 127;
    const int r  = blockIdx.x*4 + gi;
    const int wid = j >> 6, lane = j & 63;
    if (j < 64) xs[gi][j] = psi[r*64 + j];
    __syncthreads();
    float x = mlp_layer_fb<64>(xs[gi], red[gi], W0, b0, g0, be0, j, wid, lane);
    __syncthreads();
    xs[gi][j] = x;
    __syncthreads();
    x = mlp_layer_fb<128>(xs[gi], red[gi], W1, b1, g1, be1, j, wid, lane);
    __syncthreads();
    xs[gi][j] = x;
    __syncthreads();
    x = mlp_layer_fb<128>(xs[gi], red[gi], W2, b2, g2, be2, j, wid, lane);
    xf[r*128 + j] = x;
}

// ---------------- Kernel 2: WvT riders (blocks 0..TBLK-1) + MFMA sweep (TBLK..) ----------------
// ROUND-39: riders moved to the FRONT of the grid. At blockIdx >= CBLK they dispatched
// LAST and serialized as a pure-BW tail (~51MB; collect grew 65.7->70us when added).
// First-position riders fill CUs during ramp-up and vacate; the latency-bound MFMA blocks
// lose nothing to co-resident BW work. XCD seg-map now uses the ACTUAL XCD of the shifted
// range: xcd = (g + (TBLK&7)) & 7 (TBLK=788 -> +4); bijectivity over (seg,rowpair)
// verified (g=8q+r -> seg=((r+4)&7)*4+(q>>6), rowpr=q&63, each pair hit exactly once).
// Both role bodies byte-identical to r18 -> candidate set and numerics unchanged.
__global__ __launch_bounds__(256, 3) void collect_kernel(
    const __bf16* __restrict__ xb, const __bf16* __restrict__ WvTb,
    const float* __restrict__ gw2s, const float* __restrict__ nrm2,
    unsigned* __restrict__ cnt, int* __restrict__ candcol,
    const float* __restrict__ Wv, float* __restrict__ WvT)
{
    __shared__ union {
        struct {
            float tauf[64];
            __bf16 xls[8192];               // [sub=ks*2+h][row 0..63][8 elems] = 16 KB
            unsigned short lcol[64][LCAP];  // per-row staged cols (u16: VDIM < 65536)
            unsigned lcnt[64];
        } c;
        float t[32*260];                    // WvT transpose staging (33.3 KB)
    } sm;
    const int tid = threadIdx.x;

    if (blockIdx.x < TBLK) {
        // ================= WvT transpose role (riders first) =================
        const int tb = blockIdx.x;
        const int c0 = (tb % 197) * 256;
        const int k0 = (tb / 197) * 32;
        const int j = tid >> 3;
        #pragma unroll
        for (int m = 0; m < 8; ++m) {
            int c = (tid & 7)*4 + m*32;
            int col = c0 + c;
            float4 v;
            if (col + 3 < VDIM) v = *(const float4*)(Wv + (size_t)(k0 + j)*VDIM + col);
            else {
                float tmp[4];
                #pragma unroll
                for (int q = 0; q < 4; ++q) tmp[q] = (col + q < VDIM) ? Wv[(size_t)(k0+j)*VDIM + col + q] : 0.f;
                v = make_float4(tmp[0], tmp[1], tmp[2], tmp[3]);
            }
            *(float4*)(sm.t + j*260 + c) = v;
        }
        __syncthreads();
        const int col = c0 + tid;
        if (col < VDIM) {
            float* dst = WvT + (size_t)col*128 + k0;
            #pragma unroll
            for (int m = 0; m < 8; ++m) {
                float4 v;
                v.x = sm.t[(m*4+0)*260 + tid];
                v.y = sm.t[(m*4+1)*260 + tid];
                v.z = sm.t[(m*4+2)*260 + tid];
                v.w = sm.t[(m*4+3)*260 + tid];
                *(float4*)(dst + m*4) = v;
            }
        }
        return;
    }

    // ================= MFMA collect role =================
    const int g     = blockIdx.x - TBLK;              // 0..CBLK-1
    const int xcd   = (g + (TBLK & 7)) & 7;           // ACTUAL XCD = blockIdx.x % 8
    const int idx   = g >> 3;                         // 0..255
    const int seg   = xcd * (NSEG/8) + (idx >> 6);    // 4 segments per XCD
    const int rowpr = idx & 63;                       // 0..63
    const int row0  = rowpr * 64;
    const int w     = tid >> 6;
    const int l     = tid & 63;
    const int lr    = l & 31;
    const int h     = l >> 5;
    const int h4    = h * 4;
    const int t0    = (NTILES * seg) >> 5;
    const int t1    = (NTILES * (seg + 1)) >> 5;

    // stage x rows (64 x 128 bf16) into fragment-major LDS; conflict-free writes
    #pragma unroll
    for (int m = 0; m < 4; ++m) {
        int cid = m*256 + tid;         // 0..1023
        int rr  = cid & 63;            // row within block
        int sub = cid >> 6;            // ks*2+h, 0..15
        *(uint4*)(sm.c.xls + sub*512 + rr*8) =
            *(const uint4*)(xb + (size_t)(row0 + rr)*128 + sub*8);
    }
    if (tid < 64) {
        float sw = sqrtf(gw2_sum(gw2s) * (1.f / (128.f * (float)VDIM)));
        sm.c.tauf[tid] = ALPHA * sw * sqrtf(nrm2[row0 + tid]);
        sm.c.lcnt[tid] = 0u;
    }
    __syncthreads();
    const float tfA = sm.c.tauf[lr];
    const float tfB = sm.c.tauf[32 + lr];

    // hit emission: LDS staging; rare overflow -> direct global (exact set preserved)
    auto EMIT = [&](int rl, int col) {
        unsigned p = atomicAdd(&sm.c.lcnt[rl], 1u);
        if (p < (unsigned)LCAP) sm.c.lcol[rl][p] = (unsigned short)col;
        else {
            unsigned gg = atomicAdd(&cnt[row0 + rl], 1u);
            if (gg < (unsigned)CAP) candcol[(size_t)(row0 + rl)*CAP + gg] = col;
        }
    };

    const __bf16* xpA = sm.c.xls + h*512 + lr*8;   // + ks*1024 (set A), +256 more for set B
    const __bf16* pa  = WvTb + (size_t)t0*32768 + (size_t)h*2048 + (size_t)(w*64 + lr)*8;

    for (int t = t0; t < t1; ++t) {
        // issue ALL 16 W-fragment loads of this tile
        bf16x8 f[16];
        #pragma unroll
        for (int ks = 0; ks < 8; ++ks) {
            f[2*ks]   = *(const bf16x8*)(pa + ks*4096);
            f[2*ks+1] = *(const bf16x8*)(pa + ks*4096 + 256);
        }
        pa += 32768;
        // fence: loads above may not sink below
        __builtin_amdgcn_sched_barrier(0);

        f32x16 a0, a1, b0, b1;
        #pragma unroll
        for (int i = 0; i < 16; ++i) { a0[i] = 0.f; a1[i] = 0.f; b0[i] = 0.f; b1[i] = 0.f; }
        #pragma unroll
        for (int ks = 0; ks < 8; ++ks) {
            bf16x8 xa = *(const bf16x8*)(xpA + ks*1024);
            bf16x8 xv = *(const bf16x8*)(xpA + ks*1024 + 256);
            a0 = __builtin_amdgcn_mfma_f32_32x32x16_bf16(f[2*ks],   xa, a0, 0, 0, 0);
            a1 = __builtin_amdgcn_mfma_f32_32x32x16_bf16(f[2*ks+1], xa, a1, 0, 0, 0);
            b0 = __builtin_amdgcn_mfma_f32_32x32x16_bf16(f[2*ks],   xv, b0, 0, 0, 0);
            b1 = __builtin_amdgcn_mfma_f32_32x32x16_bf16(f[2*ks+1], xv, b1, 0, 0, 0);
        }
        const int cb = (t << 8) + w*64 + h4;   // per-lane column base
        // Pad columns (col >= VDIM) score 0 < tau; col<VDIM check before emission.
        // Grouped screen: 4 values share one fmax-tree test; per-value compares inside
        // are unchanged -> candidate set provably identical.
        #pragma unroll
        for (int i = 0; i < 16; i += 4) {
            const int gb = 8 * (i >> 2);
            if (fmaxf(fmaxf(a0[i], a0[i+1]), fmaxf(a0[i+2], a0[i+3])) >= tfA) {
                #pragma unroll
                for (int q = 0; q < 4; ++q) {
                    if (a0[i+q] >= tfA) {
                        int col = cb + gb + q;
                        if (col < VDIM) EMIT(lr, col);
                    }
                }
            }
            if (fmaxf(fmaxf(a1[i], a1[i+1]), fmaxf(a1[i+2], a1[i+3])) >= tfA) {
                #pragma unroll
                for (int q = 0; q < 4; ++q) {
                    if (a1[i+q] >= tfA) {
                        int col = cb + 32 + gb + q;
                        if (col < VDIM) EMIT(lr, col);
                    }
                }
            }
            if (fmaxf(fmaxf(b0[i], b0[i+1]), fmaxf(b0[i+2], b0[i+3])) >= tfB) {
                #pragma unroll
                for (int q = 0; q < 4; ++q) {
                    if (b0[i+q] >= tfB) {
                        int col = cb + gb + q;
                        if (col < VDIM) EMIT(32 + lr, col);
                    }
                }
            }
            if (fmaxf(fmaxf(b1[i], b1[i+1]), fmaxf(b1[i+2], b1[i+3])) >= tfB) {
                #pragma unroll
                for (int q = 0; q < 4; ++q) {
                    if (b1[i+q] >= tfB) {
                        int col = cb + 32 + gb + q;
                        if (col < VDIM) EMIT(32 + lr, col);
                    }
                }
            }
        }
    }

    // ---- flush: one per-lane global atomic per row per block, then copy lists out ----
    __syncthreads();
    if (tid < 64) {
        unsigned nl = sm.c.lcnt[tid];
        if (nl > (unsigned)LCAP) nl = (unsigned)LCAP;
        if (nl) {
            const int row = row0 + tid;
            unsigned base = atomicAdd(&cnt[row], nl);
            for (unsigned i = 0; i < nl; ++i) {
                unsigned pp = base + i;
                if (pp < (unsigned)CAP) candcol[(size_t)row*CAP + pp] = (int)sm.c.lcol[tid][i];
            }
        }
    }
}

// ---------------- Kernel 3: merged rescore+fixup per row ----------------
// strict-count guard computed HERE from exact fp32 dots (ballot+popc): >=TOPK candidates
// with exact dot >= ts = tf + 2D beats every uncollected column (bf16 < tf => exact < tf + D).
__global__ __launch_bounds__(64) void final_kernel(
    const unsigned* __restrict__ cnt, const int* __restrict__ candcol,
    const float* __restrict__ xf, const float* __restrict__ WvT,
    const float* __restrict__ bv, const float* __restrict__ qv, float* __restrict__ out,
    const float* __restrict__ gw2s, const float* __restrict__ nrm1, const float* __restrict__ nrm2)
{
    const int row = blockIdx.x;
    const unsigned n_all = cnt[row];
    const int l = threadIdx.x;
    const float4* xp = (const float4*)(xf + (size_t)row*128);
    float wk[TOPK]; int ik[TOPK];
    bool done = false;

    if (n_all <= (unsigned)CAP) {
        // ---- rescore path: exact fp32 over <=CAP candidates, skip empty slot-groups ----
        const int ng = ((int)n_all + 63) >> 6;
        int c[3]; float vv[3], dd[3];
        #pragma unroll
        for (int s = 0; s < 3; ++s) {
            c[s] = 0x7fffffff; vv[s] = -1e38f; dd[s] = -1e38f;
            if (s < ng) {
                bool ok = (l + s*64 < (int)n_all);
                int cc2 = ok ? candcol[(size_t)row*CAP + l + s*64] : 0;
                const float4* wp = (const float4*)(WvT + (size_t)cc2*128);
                float s0 = 0.f, s1 = 0.f, s2 = 0.f, s3 = 0.f;
                #pragma unroll
                for (int j = 0; j < 32; ++j) {
                    float4 x4 = xp[j], w4 = wp[j];
                    s0 = fmaf(x4.x, w4.x, s0); s1 = fmaf(x4.y, w4.y, s1);
                    s2 = fmaf(x4.z, w4.z, s2); s3 = fmaf(x4.w, w4.w, s3);
                }
                float dot = (s0 + s1) + (s2 + s3);
                if (ok) { dd[s] = dot; vv[s] = dot + bv[cc2]; c[s] = cc2; }
            }
        }
        float sw = sqrtf(gw2_sum(gw2s) * (1.f / (128.f * (float)VDIM)));
        float ts = ALPHA * sw * sqrtf(nrm2[row]) + DELTA_C * nrm1[row];
        int nstr = 0;
        #pragma unroll
        for (int s = 0; s < 3; ++s) nstr += (int)__popcll(__ballot(dd[s] >= ts));
        if (nstr >= TOPK) {
            #pragma unroll
            for (int k = 0; k < TOPK; ++k) {
                float mv = vv[0]; int mi = c[0];
                if (tk_better(vv[1], c[1], mv, mi)) { mv = vv[1]; mi = c[1]; }
                if (tk_better(vv[2], c[2], mv, mi)) { mv = vv[2]; mi = c[2]; }
                #pragma unroll
                for (int m = 1; m < 64; m <<= 1) {
                    float ov = __shfl_xor(mv, m);
                    int oi = __shfl_xor(mi, m);
                    if (tk_better(ov, oi, mv, mi)) { mv = ov; mi = oi; }
                }
                wk[k] = mv; ik[k] = mi;
                #pragma unroll
                for (int s = 0; s < 3; ++s) if (c[s] == mi) vv[s] = -1e38f;   // cols unique per row
            }
            done = true;
        }
    }
    if (!done) {
        // ---- fixup path: exact full scan (guard failed; ~never) ----
        float tv[TOPK]; int ti[TOPK];
        #pragma unroll
        for (int k = 0; k < TOPK; ++k) { tv[k] = -1e38f; ti[k] = 0x7fffffff; }
        for (int c2 = l; c2 < VDIM; c2 += 64) {
            const float4* wp = (const float4*)(WvT + (size_t)c2*128);
            float s0 = 0.f, s1 = 0.f, s2 = 0.f, s3 = 0.f;
            #pragma unroll
            for (int j = 0; j < 32; ++j) {
                float4 x4 = xp[j], w4 = wp[j];
                s0 = fmaf(x4.x, w4.x, s0); s1 = fmaf(x4.y, w4.y, s1);
                s2 = fmaf(x4.z, w4.z, s2); s3 = fmaf(x4.w, w4.w, s3);
            }
            tk_insertT<TOPK>(((s0 + s1) + (s2 + s3)) + bv[c2], c2, tv, ti);
        }
        int p = 0;
        for (int k = 0; k < TOPK; ++k) {
            float hv = -1e38f; int hc = 0x7fffffff;
            #pragma unroll
            for (int q = 0; q < TOPK; ++q) if (q == p) { hv = tv[q]; hc = ti[q]; }
            float mv = hv; int mi = hc;
            #pragma unroll
            for (int m = 1; m < 64; m <<= 1) {
                float ov = __shfl_xor(mv, m);
                int oi = __shfl_xor(mi, m);
                if (tk_better(ov, oi, mv, mi)) { mv = ov; mi = oi; }
            }
            wk[k] = mv; ik[k] = mi;
            if (hc == mi) ++p;
        }
    }

    float m0 = wk[0];
    float tot = 0.f;
    #pragma unroll
    for (int k = 0; k < TOPK; ++k) { wk[k] = expf(wk[k] - m0); tot += wk[k]; }
    float it = 1.f / tot;
    #pragma unroll
    for (int e = 0; e < 4; ++e) {
        int ei = l + e*64;
        float acc = 0.f;
        #pragma unroll
        for (int k = 0; k < TOPK; ++k) acc = fmaf(wk[k], qv[(size_t)ik[k]*256 + ei], acc);
        out[(size_t)row*256 + ei] = acc * it;
    }
}

// ================= OLD (fallback) path: fp32 VALU GEMM + fused top-10 =================
__global__ __launch_bounds__(256, 2) void logits_topk_kernel(
    const float* __restrict__ xf, const float* __restrict__ Wv,
    const float* __restrict__ bv, float2* __restrict__ cand)
{
    __shared__ __align__(16) float xsT[128*36];
    __shared__ __align__(16) float lt[32*260];
    const int chunk = blockIdx.x;
    const int row0  = blockIdx.y * BM;
    const int tid   = threadIdx.x;
    #pragma unroll
    for (int i = 0; i < 16; ++i) {
        int idx = i*256 + tid;
        int rr = idx >> 7, k = idx & 127;
        xsT[k*36 + rr] = xf[(row0 + rr)*128 + k];
    }
    __syncthreads();
    const int ri = tid >> 6;
    const int ci = tid & 63;
    const int srow = tid & 31;
    const int ssub = tid >> 5;
    const int cbase = chunk * TV;
    float tv[TOPK]; int tix[TOPK];
    #pragma unroll
    for (int k = 0; k < TOPK; ++k) { tv[k] = -1e38f; tix[k] = 0x7fffffff; }
    for (int cs = 0; cs < TV; cs += 256) {
        int c[4], cl[4];
        #pragma unroll
        for (int q = 0; q < 4; ++q) {
            c[q]  = cbase + cs + q*64 + ci;
            cl[q] = c[q] < VDIM ? c[q] : VDIM-1;
        }
        float acc[8][4];
        #pragma unroll
        for (int r = 0; r < 8; ++r)
            #pragma unroll
            for (int q = 0; q < 4; ++q) acc[r][q] = 0.f;
        const float* xp = xsT + ri*8;
        #pragma unroll 2
        for (int k = 0; k < 128; ++k) {
            const float* wr = Wv + (size_t)k * VDIM;
            float w0 = wr[cl[0]], w1 = wr[cl[1]], w2 = wr[cl[2]], w3 = wr[cl[3]];
            float4 xa = *(const float4*)(xp + k*36);
            float4 xb2 = *(const float4*)(xp + k*36 + 4);
            float xr[8] = {xa.x, xa.y, xa.z, xa.w, xb2.x, xb2.y, xb2.z, xb2.w};
            #pragma unroll
            for (int r = 0; r < 8; ++r) {
                acc[r][0] = fmaf(xr[r], w0, acc[r][0]);
                acc[r][1] = fmaf(xr[r], w1, acc[r][1]);
                acc[r][2] = fmaf(xr[r], w2, acc[r][2]);
                acc[r][3] = fmaf(xr[r], w3, acc[r][3]);
            }
        }
        #pragma unroll
        for (int q = 0; q < 4; ++q) {
            float bq = bv[cl[q]];
            bool valid = c[q] < VDIM;
            #pragma unroll
            for (int r = 0; r < 8; ++r)
                acc[r][q] = valid ? (acc[r][q] + bq) : -1e30f;
        }
        #pragma unroll
        for (int r = 0; r < 8; ++r) {
            float* lrow = lt + (ri*8 + r)*260;
            #pragma unroll
            for (int q = 0; q < 4; ++q) lrow[q*64 + ci] = acc[r][q];
        }
        __syncthreads();
        const float* srp = lt + srow*260 + ssub*32;
        #pragma unroll
        for (int j = 0; j < 32; j += 4) {
            float4 v4 = *(const float4*)(srp + j);
            int cc = cbase + cs + ssub*32 + j;
            tk_insertT<TOPK>(v4.x, cc+0, tv, tix);
            tk_insertT<TOPK>(v4.y, cc+1, tv, tix);
            tk_insertT<TOPK>(v4.z, cc+2, tv, tix);
            tk_insertT<TOPK>(v4.w, cc+3, tv, tix);
        }
        __syncthreads();
    }
    float* cbuf = lt;
    {
        float* myb = cbuf + (srow*8 + ssub)*TOPK*2;
        #pragma unroll
        for (int k = 0; k < TOPK; ++k) { myb[2*k] = tv[k]; myb[2*k+1] = __int_as_float(tix[k]); }
    }
    __syncthreads();
    if (tid < BM) {
        float mv[TOPK]; int mi[TOPK];
        #pragma unroll
        for (int k = 0; k < TOPK; ++k) { mv[k] = -1e38f; mi[k] = 0x7fffffff; }
        for (int s = 0; s < 8; ++s) {
            const float* cb = cbuf + (tid*8 + s)*TOPK*2;
            for (int k = 0; k < TOPK; ++k) {
                float v = cb[2*k]; int ix = __float_as_int(cb[2*k+1]);
                if (!tk_better(v, ix, mv[TOPK-1], mi[TOPK-1])) break;
                tk_insertT<TOPK>(v, ix, mv, mi);
            }
        }
        float2* outp = cand + ((size_t)(row0 + tid)*NC + chunk)*TOPK;
        #pragma unroll
        for (int k = 0; k < TOPK; ++k) outp[k] = make_float2(mv[k], __int_as_float(mi[k]));
    }
}

__global__ __launch_bounds__(64) void finalize_kernel(
    const float2* __restrict__ cand, const float* __restrict__ qv, float* __restrict__ out)
{
    const int row = blockIdx.x;
    __shared__ float wk[TOPK];
    __shared__ int   ik[TOPK];
    __shared__ float invtot;
    if (threadIdx.x == 0) {
        float mv[TOPK]; int mi[TOPK];
        #pragma unroll
        for (int k = 0; k < TOPK; ++k) { mv[k] = -1e38f; mi[k] = 0x7fffffff; }
        for (int ch = 0; ch < NC; ++ch) {
            const float2* cp = cand + ((size_t)row*NC + ch)*TOPK;
            for (int k = 0; k < TOPK; ++k) {
                float2 cv = cp[k];
                int ix = __float_as_int(cv.y);
                if (!tk_better(cv.x, ix, mv[TOPK-1], mi[TOPK-1])) break;
                tk_insertT<TOPK>(cv.x, ix, mv, mi);
            }
        }
        float m = mv[0];
        float t = 0.f;
        #pragma unroll
        for (int k = 0; k < TOPK; ++k) { float w = expf(mv[k] - m); wk[k] = w; ik[k] = mi[k]; t += w; }
        invtot = 1.f / t;
    }
    __syncthreads();
    const int l = threadIdx.x;
    float it = invtot;
    #pragma unroll
    for (int e = 0; e < 4; ++e) {
        int ei = l + e*64;
        float s = 0.f;
        #pragma unroll
        for (int k = 0; k < TOPK; ++k) s = fmaf(wk[k], qv[(size_t)ik[k]*256 + ei], s);
        out[(size_t)row*256 + ei] = s * it;
    }
}

extern "C" void kernel_launch(void* const* d_in, const int* in_sizes, int n_in,
                              void* d_out, int out_size, void* d_ws, size_t ws_size,
                              hipStream_t stream)
{
    const float* psi = (const float*)d_in[0];
    const float* qv  = (const float*)d_in[1];
    const float* W0  = (const float*)d_in[2];
    const float* b0  = (const float*)d_in[3];
    const float* g0  = (const float*)d_in[4];
    const float* be0 = (const float*)d_in[5];
    const float* W1  = (const float*)d_in[6];
    const float* b1  = (const float*)d_in[7];
    const float* g1  = (const float*)d_in[8];
    const float* be1 = (const float*)d_in[9];
    const float* W2  = (const float*)d_in[10];
    const float* b2  = (const float*)d_in[11];
    const float* g2  = (const float*)d_in[12];
    const float* be2 = (const float*)d_in[13];
    const float* Wv  = (const float*)d_in[14];
    const float* bv  = (const float*)d_in[15];
    float* out = (float*)d_out;

    auto al = [](size_t x) { return (x + 255) & ~(size_t)255; };
    const size_t o_xf   = 0;
    const size_t o_xb   = al(o_xf + (size_t)NROWS*128*4);
    const size_t o_wvt  = al(o_xb + (size_t)NROWS*128*2);
    const size_t o_wvtb = al(o_wvt + (size_t)VDIM*128*4);
    const size_t o_nrm1 = al(o_wvtb + (size_t)PADV*128*2);
    const size_t o_nrm2 = al(o_nrm1 + (size_t)NROWS*4);
    const size_t o_gw2  = al(o_nrm2 + (size_t)NROWS*4);
    const size_t o_cnt  = al(o_gw2 + 1024);      // 8 cacheline-spaced slots
    const size_t o_cand = al(o_cnt + (size_t)NROWS*4);
    const size_t need   = al(o_cand + (size_t)NROWS*CAP*4);

    if (ws_size >= need) {
        float*    xf   = (float*)((char*)d_ws + o_xf);
        __bf16*   xb   = (__bf16*)((char*)d_ws + o_xb);
        float*    WvT  = (float*)((char*)d_ws + o_wvt);
        __bf16*   WvTb = (__bf16*)((char*)d_ws + o_wvtb);
        float*    nrm1 = (float*)((char*)d_ws + o_nrm1);
        float*    nrm2 = (float*)((char*)d_ws + o_nrm2);
        float*    gw2s = (float*)((char*)d_ws + o_gw2);
        unsigned* cnt  = (unsigned*)((char*)d_ws + o_cnt);
        int*      cc   = (int*)((char*)d_ws + o_cand);
        // zero gw2 slots + cnt in one async memset (graph-capture-safe)
        hipMemsetAsync((char*)d_ws + o_gw2, 0, o_cand - o_gw2, stream);
        transpose_kernel<<<TBLK, 256, 0, stream>>>(Wv, WvTb, gw2s);
        mlp16_kernel<<<NROWS/16, 512, 0, stream>>>(
            psi, W0, b0, g0, be0, W1, b1, g1, be1, W2, b2, g2, be2,
            xf, xb, nrm1, nrm2);
        collect_kernel<<<CBLK + TBLK, 256, 0, stream>>>(xb, WvTb, gw2s, nrm2, cnt, cc, Wv, WvT);
        final_kernel<<<NROWS, 64, 0, stream>>>(cnt, cc, xf, WvT, bv, qv, out, gw2s, nrm1, nrm2);
    } else {
        // fallback: fp32 VALU path (round-1 verified)
        float* xf = (float*)d_ws;
        float2* cand = (float2*)((char*)d_ws + (size_t)NROWS*128*sizeof(float));
        mlp_kernel<<<NROWS/4, 512, 0, stream>>>(psi, W0, b0, g0, be0, W1, b1, g1, be1, W2, b2, g2, be2, xf);
        logits_topk_kernel<<<dim3(NC, NROWS/BM), 256, 0, stream>>>(xf, Wv, bv, cand);
        finalize_kernel<<<NROWS, 64, 0, stream>>>(cand, qv, out);
    }
}

// Round 20
// 129.179 us; speedup vs baseline: 1.0360x; 1.0360x over previous
//
#include <hip/hip_runtime.h>
#include <hip/hip_bf16.h>

#define TOPK 10
#define LN_EPS 1e-5f
#define NROWS 4096
#define VDIM 50257
#define PADV 50432     // VDIM padded to 256 (197 tiles)
#define NTILES 197
#define TBLK 788       // transpose blocks (197 c-tiles x 4 k-groups)
#define CBLK 2048      // collect MFMA-role blocks
#define XPAD 20        // xsT row pad (floats)
// old (fallback) path
#define NC 13
#define TV 4096
#define BM 32
// new path
#define NSEG 32        // tile segments (6-7 tiles each)
#define CAP 192        // per-row candidate buffer slots
#define LCAP 16        // per-(row,block) LDS staging slots (P(overflow) ~ 1e-10)
#define ALPHA 3.0f     // tau = ALPHA * sigma_w * ||x||_2  (E[collect] ~ 68/row)
#define DELTA_C 2.5e-4f // strict margin per ||x||_1 >= 2*eps_bf16

typedef __bf16 bf16x8 __attribute__((ext_vector_type(8)));
typedef float f32x16 __attribute__((ext_vector_type(16)));

__device__ __forceinline__ bool tk_better(float v1, int i1, float v2, int i2) {
    return v1 > v2 || (v1 == v2 && i1 < i2);
}

// sum the 8 cacheline-spaced gw2 partial slots — IDENTICAL order in collect and final
__device__ __forceinline__ float gw2_sum(const float* __restrict__ gw2s) {
    float g = 0.f;
    #pragma unroll
    for (int i = 0; i < 8; ++i) g += gw2s[i*32];
    return g;
}

template<int K>
__device__ __forceinline__ void tk_insertT(float v, int ix, float (&tv)[K], int (&tix)[K]) {
    if (!tk_better(v, ix, tv[K-1], tix[K-1])) return;
    #pragma unroll
    for (int q = K - 1; q > 0; --q) {
        bool bqm1 = tk_better(v, ix, tv[q-1], tix[q-1]);
        bool bq   = tk_better(v, ix, tv[q],   tix[q]);
        float nv = bqm1 ? tv[q-1] : (bq ? v : tv[q]);
        int   ni = bqm1 ? tix[q-1] : (bq ? ix : tix[q]);
        tv[q] = nv; tix[q] = ni;
    }
    if (tk_better(v, ix, tv[0], tix[0])) { tv[0] = v; tix[0] = ix; }
}

// ---------------- Kernel T: WvTb transpose + gw2 partials ----------------
// ROUND-40: FINAL — restore verified-best r18 structure (129.6us; session best 129.3).
// r19's riders-first regressed (+4.2us): in-order occupancy-limited dispatch means 788
// BW riders at the grid front DELAY the long-pole MFMA blocks rather than hiding under
// them. Riders-last (here) lets MFMA start immediately; rider tail partially overlaps
// MFMA stragglers. Both orderings measured; this one wins.
// r36 win: per-block LDS reduce -> ONE atomic per block into 8 cacheline-spaced slots
// (the old single-cacheline gw2 atomic was a ~65us chip-wide serializer).
__global__ __launch_bounds__(256) void transpose_kernel(
    const float* __restrict__ Wv, __bf16* __restrict__ WvTb,
    float* __restrict__ gw2s)
{
    __shared__ float t[32*260];
    __shared__ float gpart[4];
    const int c0 = (blockIdx.x % 197) * 256;
    const int k0 = (blockIdx.x / 197) * 32;
    const int tid = threadIdx.x;
    const int j = tid >> 3;
    #pragma unroll
    for (int m = 0; m < 8; ++m) {
        int c = (tid & 7)*4 + m*32;
        int col = c0 + c;
        float4 v;
        if (col + 3 < VDIM) v = *(const float4*)(Wv + (size_t)(k0 + j)*VDIM + col);
        else {
            float tmp[4];
            #pragma unroll
            for (int q = 0; q < 4; ++q) tmp[q] = (col + q < VDIM) ? Wv[(size_t)(k0+j)*VDIM + col + q] : 0.f;
            v = make_float4(tmp[0], tmp[1], tmp[2], tmp[3]);
        }
        *(float4*)(t + j*260 + c) = v;
    }
    __syncthreads();
    const int col = c0 + tid;
    // plane-major bf16 (pads zero-filled)
    const int tile = c0 >> 8;
    #pragma unroll
    for (int jg = 0; jg < 4; ++jg) {
        const int kbase = k0 + jg*8;
        const int ks = kbase >> 4, kh = (kbase >> 3) & 1;
        __bf16 bb[8];
        if (col < VDIM) {
            #pragma unroll
            for (int i = 0; i < 8; ++i) bb[i] = (__bf16)t[(jg*8 + i)*260 + tid];
        } else {
            #pragma unroll
            for (int i = 0; i < 8; ++i) bb[i] = (__bf16)0.f;
        }
        *(uint4*)(WvTb + (size_t)tile*32768 + (size_t)(ks*2 + kh)*2048 + (size_t)tid*8) = *(uint4*)bb;
    }
    float p = 0.f;
    if (col < VDIM) {
        #pragma unroll
        for (int i = 0; i < 32; ++i) { float v = t[i*260 + tid]; p = fmaf(v, v, p); }
    }
    #pragma unroll
    for (int m = 1; m < 64; m <<= 1) p += __shfl_xor(p, m);
    if ((tid & 63) == 0) gpart[tid >> 6] = p;
    __syncthreads();
    if (tid == 0)
        atomicAdd(&gw2s[(blockIdx.x & 7) * 32],
                  (gpart[0] + gpart[1]) + (gpart[2] + gpart[3]));
}

// ---------------- Kernel M: mlp, 16 rows/block, 4-row register reuse ----------------
__global__ __launch_bounds__(512) void mlp16_kernel(
    const float* __restrict__ psi,
    const float* __restrict__ W0, const float* __restrict__ b0, const float* __restrict__ g0, const float* __restrict__ be0,
    const float* __restrict__ W1, const float* __restrict__ b1, const float* __restrict__ g1, const float* __restrict__ be1,
    const float* __restrict__ W2, const float* __restrict__ b2, const float* __restrict__ g2, const float* __restrict__ be2,
    float* __restrict__ xf, __bf16* __restrict__ xb,
    float* __restrict__ nrm1, float* __restrict__ nrm2)
{
    __shared__ float wbuf[128*128];         // staged W layer (64 KB)
    __shared__ float xsT[128*XPAD];         // x transposed: [k][16 rows], padded (10 KB)
    __shared__ float4 red1[8], red2[8];
    const int tid  = threadIdx.x;
    const int row0 = blockIdx.x * 16;
    const int q    = tid >> 7;     // row-quad 0..3 (rows 4q..4q+3)
    const int j    = tid & 127;    // output col
    const int w    = tid >> 6;     // wave 0..7
    const int l    = tid & 63;

    // stage W0 (64x128 = 2048 float4) + psi -> xsT
    #pragma unroll
    for (int m = 0; m < 4; ++m) {
        int idx = m*512 + tid;
        *(float4*)(wbuf + idx*4) = *(const float4*)(W0 + idx*4);
    }
    #pragma unroll
    for (int m = 0; m < 2; ++m) {
        int idx = m*512 + tid;         // 0..1023
        int k = idx & 63, r = idx >> 6;
        xsT[k*XPAD + r] = psi[(size_t)(row0 + r)*64 + k];
    }
    __syncthreads();

    float y[4];
    // ---- layer 0 (K=64), stage W1 in the B1->B2 window ----
    {
        float a0 = 0.f, a1 = 0.f, a2 = 0.f, a3 = 0.f;
        #pragma unroll 8
        for (int k = 0; k < 64; ++k) {
            float wv = wbuf[k*128 + j];
            float4 xv = *(const float4*)(xsT + k*XPAD + q*4);
            a0 = fmaf(xv.x, wv, a0); a1 = fmaf(xv.y, wv, a1);
            a2 = fmaf(xv.z, wv, a2); a3 = fmaf(xv.w, wv, a3);
        }
        const float bj = b0[j];
        const float v0 = a0 + bj, v1 = a1 + bj, v2 = a2 + bj, v3 = a3 + bj;
        float s0 = v0, s1 = v1, s2 = v2, s3 = v3;
        #pragma unroll
        for (int m = 1; m < 64; m <<= 1) {
            s0 += __shfl_xor(s0, m); s1 += __shfl_xor(s1, m);
            s2 += __shfl_xor(s2, m); s3 += __shfl_xor(s3, m);
        }
        if (l == 0) red1[w] = make_float4(s0, s1, s2, s3);
        __syncthreads();
        #pragma unroll
        for (int m = 0; m < 8; ++m) {
            int idx = m*512 + tid;
            *(float4*)(wbuf + idx*4) = *(const float4*)(W1 + idx*4);
        }
        float4 ra = red1[2*q], rb = red1[2*q+1];
        const float mu0 = (ra.x + rb.x)*(1.f/128.f), mu1 = (ra.y + rb.y)*(1.f/128.f);
        const float mu2 = (ra.z + rb.z)*(1.f/128.f), mu3 = (ra.w + rb.w)*(1.f/128.f);
        const float d0 = v0-mu0, d1 = v1-mu1, d2 = v2-mu2, d3 = v3-mu3;
        float t0 = d0*d0, t1 = d1*d1, t2 = d2*d2, t3 = d3*d3;
        #pragma unroll
        for (int m = 1; m < 64; m <<= 1) {
            t0 += __shfl_xor(t0, m); t1 += __shfl_xor(t1, m);
            t2 += __shfl_xor(t2, m); t3 += __shfl_xor(t3, m);
        }
        if (l == 0) red2[w] = make_float4(t0, t1, t2, t3);
        __syncthreads();
        float4 va = red2[2*q], vb = red2[2*q+1];
        const float gj = g0[j], bej = be0[j];
        y[0] = fmaxf(d0*rsqrtf((va.x+vb.x)*(1.f/128.f)+LN_EPS)*gj + bej, 0.f);
        y[1] = fmaxf(d1*rsqrtf((va.y+vb.y)*(1.f/128.f)+LN_EPS)*gj + bej, 0.f);
        y[2] = fmaxf(d2*rsqrtf((va.z+vb.z)*(1.f/128.f)+LN_EPS)*gj + bej, 0.f);
        y[3] = fmaxf(d3*rsqrtf((va.w+vb.w)*(1.f/128.f)+LN_EPS)*gj + bej, 0.f);
    }
    #pragma unroll
    for (int i = 0; i < 4; ++i) xsT[j*XPAD + q*4 + i] = y[i];
    __syncthreads();
    // ---- layer 1 (K=128), stage W2 in window ----
    {
        float a0 = 0.f, a1 = 0.f, a2 = 0.f, a3 = 0.f;
        #pragma unroll 8
        for (int k = 0; k < 128; ++k) {
            float wv = wbuf[k*128 + j];
            float4 xv = *(const float4*)(xsT + k*XPAD + q*4);
            a0 = fmaf(xv.x, wv, a0); a1 = fmaf(xv.y, wv, a1);
            a2 = fmaf(xv.z, wv, a2); a3 = fmaf(xv.w, wv, a3);
        }
        const float bj = b1[j];
        const float v0 = a0 + bj, v1 = a1 + bj, v2 = a2 + bj, v3 = a3 + bj;
        float s0 = v0, s1 = v1, s2 = v2, s3 = v3;
        #pragma unroll
        for (int m = 1; m < 64; m <<= 1) {
            s0 += __shfl_xor(s0, m); s1 += __shfl_xor(s1, m);
            s2 += __shfl_xor(s2, m); s3 += __shfl_xor(s3, m);
        }
        if (l == 0) red1[w] = make_float4(s0, s1, s2, s3);
        __syncthreads();
        #pragma unroll
        for (int m = 0; m < 8; ++m) {
            int idx = m*512 + tid;
            *(float4*)(wbuf + idx*4) = *(const float4*)(W2 + idx*4);
        }
        float4 ra = red1[2*q], rb = red1[2*q+1];
        const float mu0 = (ra.x + rb.x)*(1.f/128.f), mu1 = (ra.y + rb.y)*(1.f/128.f);
        const float mu2 = (ra.z + rb.z)*(1.f/128.f), mu3 = (ra.w + rb.w)*(1.f/128.f);
        const float d0 = v0-mu0, d1 = v1-mu1, d2 = v2-mu2, d3 = v3-mu3;
        float t0 = d0*d0, t1 = d1*d1, t2 = d2*d2, t3 = d3*d3;
        #pragma unroll
        for (int m = 1; m < 64; m <<= 1) {
            t0 += __shfl_xor(t0, m); t1 += __shfl_xor(t1, m);
            t2 += __shfl_xor(t2, m); t3 += __shfl_xor(t3, m);
        }
        if (l == 0) red2[w] = make_float4(t0, t1, t2, t3);
        __syncthreads();
        float4 va = red2[2*q], vb = red2[2*q+1];
        const float gj = g1[j], bej = be1[j];
        y[0] = fmaxf(d0*rsqrtf((va.x+vb.x)*(1.f/128.f)+LN_EPS)*gj + bej, 0.f);
        y[1] = fmaxf(d1*rsqrtf((va.y+vb.y)*(1.f/128.f)+LN_EPS)*gj + bej, 0.f);
        y[2] = fmaxf(d2*rsqrtf((va.z+vb.z)*(1.f/128.f)+LN_EPS)*gj + bej, 0.f);
        y[3] = fmaxf(d3*rsqrtf((va.w+vb.w)*(1.f/128.f)+LN_EPS)*gj + bej, 0.f);
    }
    #pragma unroll
    for (int i = 0; i < 4; ++i) xsT[j*XPAD + q*4 + i] = y[i];
    __syncthreads();
    // ---- layer 2 (K=128) ----
    {
        float a0 = 0.f, a1 = 0.f, a2 = 0.f, a3 = 0.f;
        #pragma unroll 8
        for (int k = 0; k < 128; ++k) {
            float wv = wbuf[k*128 + j];
            float4 xv = *(const float4*)(xsT + k*XPAD + q*4);
            a0 = fmaf(xv.x, wv, a0); a1 = fmaf(xv.y, wv, a1);
            a2 = fmaf(xv.z, wv, a2); a3 = fmaf(xv.w, wv, a3);
        }
        const float bj = b2[j];
        const float v0 = a0 + bj, v1 = a1 + bj, v2 = a2 + bj, v3 = a3 + bj;
        float s0 = v0, s1 = v1, s2 = v2, s3 = v3;
        #pragma unroll
        for (int m = 1; m < 64; m <<= 1) {
            s0 += __shfl_xor(s0, m); s1 += __shfl_xor(s1, m);
            s2 += __shfl_xor(s2, m); s3 += __shfl_xor(s3, m);
        }
        if (l == 0) red1[w] = make_float4(s0, s1, s2, s3);
        __syncthreads();
        float4 ra = red1[2*q], rb = red1[2*q+1];
        const float mu0 = (ra.x + rb.x)*(1.f/128.f), mu1 = (ra.y + rb.y)*(1.f/128.f);
        const float mu2 = (ra.z + rb.z)*(1.f/128.f), mu3 = (ra.w + rb.w)*(1.f/128.f);
        const float d0 = v0-mu0, d1 = v1-mu1, d2 = v2-mu2, d3 = v3-mu3;
        float t0 = d0*d0, t1 = d1*d1, t2 = d2*d2, t3 = d3*d3;
        #pragma unroll
        for (int m = 1; m < 64; m <<= 1) {
            t0 += __shfl_xor(t0, m); t1 += __shfl_xor(t1, m);
            t2 += __shfl_xor(t2, m); t3 += __shfl_xor(t3, m);
        }
        if (l == 0) red2[w] = make_float4(t0, t1, t2, t3);
        __syncthreads();
        float4 va = red2[2*q], vb = red2[2*q+1];
        const float gj = g2[j], bej = be2[j];
        y[0] = fmaxf(d0*rsqrtf((va.x+vb.x)*(1.f/128.f)+LN_EPS)*gj + bej, 0.f);
        y[1] = fmaxf(d1*rsqrtf((va.y+vb.y)*(1.f/128.f)+LN_EPS)*gj + bej, 0.f);
        y[2] = fmaxf(d2*rsqrtf((va.z+vb.z)*(1.f/128.f)+LN_EPS)*gj + bej, 0.f);
        y[3] = fmaxf(d3*rsqrtf((va.w+vb.w)*(1.f/128.f)+LN_EPS)*gj + bej, 0.f);
    }

    // outputs (coalesced across j)
    #pragma unroll
    for (int i = 0; i < 4; ++i) {
        const int rr = row0 + q*4 + i;
        xf[(size_t)rr*128 + j] = y[i];
        xb[(size_t)rr*128 + j] = (__bf16)y[i];
    }
    // ||x||_1, ||x||_2^2 per row (y >= 0 post-ReLU)
    {
        float s0 = y[0], s1 = y[1], s2 = y[2], s3 = y[3];
        #pragma unroll
        for (int m = 1; m < 64; m <<= 1) {
            s0 += __shfl_xor(s0, m); s1 += __shfl_xor(s1, m);
            s2 += __shfl_xor(s2, m); s3 += __shfl_xor(s3, m);
        }
        if (l == 0) red1[w] = make_float4(s0, s1, s2, s3);
        float t0 = y[0]*y[0], t1 = y[1]*y[1], t2 = y[2]*y[2], t3 = y[3]*y[3];
        #pragma unroll
        for (int m = 1; m < 64; m <<= 1) {
            t0 += __shfl_xor(t0, m); t1 += __shfl_xor(t1, m);
            t2 += __shfl_xor(t2, m); t3 += __shfl_xor(t3, m);
        }
        if (l == 0) red2[w] = make_float4(t0, t1, t2, t3);
        __syncthreads();
        if (j == 0) {    // one thread per row-quad
            float4 ra = red1[2*q], rb = red1[2*q+1];
            float4 va = red2[2*q], vb = red2[2*q+1];
            nrm1[row0 + q*4 + 0] = ra.x + rb.x;
            nrm1[row0 + q*4 + 1] = ra.y + rb.y;
            nrm1[row0 + q*4 + 2] = ra.z + rb.z;
            nrm1[row0 + q*4 + 3] = ra.w + rb.w;
            nrm2[row0 + q*4 + 0] = va.x + vb.x;
            nrm2[row0 + q*4 + 1] = va.y + vb.y;
            nrm2[row0 + q*4 + 2] = va.z + vb.z;
            nrm2[row0 + q*4 + 3] = va.w + vb.w;
        }
    }
}

// ---------------- fallback-path mlp (old structure) ----------------
template<int KD>
__device__ __forceinline__ float mlp_layer_fb(const float* xs, float* red, const float* __restrict__ W,
                                              const float* __restrict__ b, const float* __restrict__ g,
                                              const float* __restrict__ be, int j, int wid, int lane) {
    float acc = b[j];
    #pragma unroll 8
    for (int k = 0; k < KD; ++k) acc = fmaf(xs[k], W[k*128 + j], acc);
    float s = acc;
    #pragma unroll
    for (int m = 1; m < 64; m <<= 1) s += __shfl_xor(s, m);
    if (lane == 0) red[wid] = s;
    __syncthreads();
    float mu = (red[0] + red[1]) * (1.f/128.f);
    float d = acc - mu;
    s = d * d;
    #pragma unroll
    for (int m = 1; m < 64; m <<= 1) s += __shfl_xor(s, m);
    __syncthreads();
    if (lane == 0) red[wid] = s;
    __syncthreads();
    float var = (red[0] + red[1]) * (1.f/128.f);
    float y = d * rsqrtf(var + LN_EPS) * g[j] + be[j];
    return fmaxf(y, 0.f);
}

__global__ __launch_bounds__(512) void mlp_kernel(
    const float* __restrict__ psi,
    const float* __restrict__ W0, const float* __restrict__ b0, const float* __restrict__ g0, const float* __restrict__ be0,
    const float* __restrict__ W1, const float* __restrict__ b1, const float* __restrict__ g1, const float* __restrict__ be1,
    const float* __restrict__ W2, const float* __restrict__ b2, const float* __restrict__ g2, const float* __restrict__ be2,
    float* __restrict__ xf)
{
    __shared__ float xs[4][128];
    __shared__ float red[4][2];
    const int gi = threadIdx.x >> 7;    // row group 0..3
    const int j  = threadIdx.x & 127;
    const int r  = blockIdx.x*4 + gi;
    const int wid = j >> 6, lane = j & 63;
    if (j < 64) xs[gi][j] = psi[r*64 + j];
    __syncthreads();
    float x = mlp_layer_fb<64>(xs[gi], red[gi], W0, b0, g0, be0, j, wid, lane);
    __syncthreads();
    xs[gi][j] = x;
    __syncthreads();
    x = mlp_layer_fb<128>(xs[gi], red[gi], W1, b1, g1, be1, j, wid, lane);
    __syncthreads();
    xs[gi][j] = x;
    __syncthreads();
    x = mlp_layer_fb<128>(xs[gi], red[gi], W2, b2, g2, be2, j, wid, lane);
    xf[r*128 + j] = x;
}

// ---------------- Kernel 2: MFMA sweep (blocks 0..2047) + WvT transpose (blocks 2048+) ----------------
// 788 WvT-producer blocks ride at the END of collect's grid (measured better than front:
// r19). WvT consumed only by final_kernel (stream-ordered). MFMA-role code and XCD
// swizzle byte-identical to r31. gw2 read as sum of 8 slots (same order as final).
// Candidate set provably identical.
__global__ __launch_bounds__(256, 3) void collect_kernel(
    const __bf16* __restrict__ xb, const __bf16* __restrict__ WvTb,
    const float* __restrict__ gw2s, const float* __restrict__ nrm2,
    unsigned* __restrict__ cnt, int* __restrict__ candcol,
    const float* __restrict__ Wv, float* __restrict__ WvT)
{
    __shared__ union {
        struct {
            float tauf[64];
            __bf16 xls[8192];               // [sub=ks*2+h][row 0..63][8 elems] = 16 KB
            unsigned short lcol[64][LCAP];  // per-row staged cols (u16: VDIM < 65536)
            unsigned lcnt[64];
        } c;
        float t[32*260];                    // WvT transpose staging (33.3 KB)
    } sm;
    const int tid = threadIdx.x;

    if (blockIdx.x >= CBLK) {
        // ================= WvT transpose role =================
        const int tb = blockIdx.x - CBLK;
        const int c0 = (tb % 197) * 256;
        const int k0 = (tb / 197) * 32;
        const int j = tid >> 3;
        #pragma unroll
        for (int m = 0; m < 8; ++m) {
            int c = (tid & 7)*4 + m*32;
            int col = c0 + c;
            float4 v;
            if (col + 3 < VDIM) v = *(const float4*)(Wv + (size_t)(k0 + j)*VDIM + col);
            else {
                float tmp[4];
                #pragma unroll
                for (int q = 0; q < 4; ++q) tmp[q] = (col + q < VDIM) ? Wv[(size_t)(k0+j)*VDIM + col + q] : 0.f;
                v = make_float4(tmp[0], tmp[1], tmp[2], tmp[3]);
            }
            *(float4*)(sm.t + j*260 + c) = v;
        }
        __syncthreads();
        const int col = c0 + tid;
        if (col < VDIM) {
            float* dst = WvT + (size_t)col*128 + k0;
            #pragma unroll
            for (int m = 0; m < 8; ++m) {
                float4 v;
                v.x = sm.t[(m*4+0)*260 + tid];
                v.y = sm.t[(m*4+1)*260 + tid];
                v.z = sm.t[(m*4+2)*260 + tid];
                v.w = sm.t[(m*4+3)*260 + tid];
                *(float4*)(dst + m*4) = v;
            }
        }
        return;
    }

    // ================= MFMA collect role (r31 body) =================
    const int wgid  = blockIdx.x;
    const int xcd   = wgid & 7;           // HW round-robin XCD assignment
    const int idx   = wgid >> 3;          // 0..255 within XCD
    const int seg   = xcd * (NSEG/8) + (idx >> 6);   // 4 segments per XCD
    const int rowpr = idx & 63;           // 0..63
    const int row0  = rowpr * 64;
    const int w     = tid >> 6;
    const int l     = tid & 63;
    const int lr    = l & 31;
    const int h     = l >> 5;
    const int h4    = h * 4;
    const int t0    = (NTILES * seg) >> 5;
    const int t1    = (NTILES * (seg + 1)) >> 5;

    // stage x rows (64 x 128 bf16) into fragment-major LDS; conflict-free writes
    #pragma unroll
    for (int m = 0; m < 4; ++m) {
        int cid = m*256 + tid;         // 0..1023
        int rr  = cid & 63;            // row within block
        int sub = cid >> 6;            // ks*2+h, 0..15
        *(uint4*)(sm.c.xls + sub*512 + rr*8) =
            *(const uint4*)(xb + (size_t)(row0 + rr)*128 + sub*8);
    }
    if (tid < 64) {
        float sw = sqrtf(gw2_sum(gw2s) * (1.f / (128.f * (float)VDIM)));
        sm.c.tauf[tid] = ALPHA * sw * sqrtf(nrm2[row0 + tid]);
        sm.c.lcnt[tid] = 0u;
    }
    __syncthreads();
    const float tfA = sm.c.tauf[lr];
    const float tfB = sm.c.tauf[32 + lr];

    // hit emission: LDS staging; rare overflow -> direct global (exact set preserved)
    auto EMIT = [&](int rl, int col) {
        unsigned p = atomicAdd(&sm.c.lcnt[rl], 1u);
        if (p < (unsigned)LCAP) sm.c.lcol[rl][p] = (unsigned short)col;
        else {
            unsigned g = atomicAdd(&cnt[row0 + rl], 1u);
            if (g < (unsigned)CAP) candcol[(size_t)(row0 + rl)*CAP + g] = col;
        }
    };

    const __bf16* xpA = sm.c.xls + h*512 + lr*8;   // + ks*1024 (set A), +256 more for set B
    const __bf16* pa  = WvTb + (size_t)t0*32768 + (size_t)h*2048 + (size_t)(w*64 + lr)*8;

    for (int t = t0; t < t1; ++t) {
        // issue ALL 16 W-fragment loads of this tile
        bf16x8 f[16];
        #pragma unroll
        for (int ks = 0; ks < 8; ++ks) {
            f[2*ks]   = *(const bf16x8*)(pa + ks*4096);
            f[2*ks+1] = *(const bf16x8*)(pa + ks*4096 + 256);
        }
        pa += 32768;
        // fence: loads above may not sink below
        __builtin_amdgcn_sched_barrier(0);

        f32x16 a0, a1, b0, b1;
        #pragma unroll
        for (int i = 0; i < 16; ++i) { a0[i] = 0.f; a1[i] = 0.f; b0[i] = 0.f; b1[i] = 0.f; }
        #pragma unroll
        for (int ks = 0; ks < 8; ++ks) {
            bf16x8 xa = *(const bf16x8*)(xpA + ks*1024);
            bf16x8 xv = *(const bf16x8*)(xpA + ks*1024 + 256);
            a0 = __builtin_amdgcn_mfma_f32_32x32x16_bf16(f[2*ks],   xa, a0, 0, 0, 0);
            a1 = __builtin_amdgcn_mfma_f32_32x32x16_bf16(f[2*ks+1], xa, a1, 0, 0, 0);
            b0 = __builtin_amdgcn_mfma_f32_32x32x16_bf16(f[2*ks],   xv, b0, 0, 0, 0);
            b1 = __builtin_amdgcn_mfma_f32_32x32x16_bf16(f[2*ks+1], xv, b1, 0, 0, 0);
        }
        const int cb = (t << 8) + w*64 + h4;   // per-lane column base
        // Pad columns (col >= VDIM) score 0 < tau; col<VDIM check before emission.
        // Grouped screen: 4 values share one fmax-tree test; per-value compares inside
        // are unchanged -> candidate set provably identical.
        #pragma unroll
        for (int i = 0; i < 16; i += 4) {
            const int gb = 8 * (i >> 2);
            if (fmaxf(fmaxf(a0[i], a0[i+1]), fmaxf(a0[i+2], a0[i+3])) >= tfA) {
                #pragma unroll
                for (int q = 0; q < 4; ++q) {
                    if (a0[i+q] >= tfA) {
                        int col = cb + gb + q;
                        if (col < VDIM) EMIT(lr, col);
                    }
                }
            }
            if (fmaxf(fmaxf(a1[i], a1[i+1]), fmaxf(a1[i+2], a1[i+3])) >= tfA) {
                #pragma unroll
                for (int q = 0; q < 4; ++q) {
                    if (a1[i+q] >= tfA) {
                        int col = cb + 32 + gb + q;
                        if (col < VDIM) EMIT(lr, col);
                    }
                }
            }
            if (fmaxf(fmaxf(b0[i], b0[i+1]), fmaxf(b0[i+2], b0[i+3])) >= tfB) {
                #pragma unroll
                for (int q = 0; q < 4; ++q) {
                    if (b0[i+q] >= tfB) {
                        int col = cb + gb + q;
                        if (col < VDIM) EMIT(32 + lr, col);
                    }
                }
            }
            if (fmaxf(fmaxf(b1[i], b1[i+1]), fmaxf(b1[i+2], b1[i+3])) >= tfB) {
                #pragma unroll
                for (int q = 0; q < 4; ++q) {
                    if (b1[i+q] >= tfB) {
                        int col = cb + 32 + gb + q;
                        if (col < VDIM) EMIT(32 + lr, col);
                    }
                }
            }
        }
    }

    // ---- flush: one per-lane global atomic per row per block, then copy lists out ----
    __syncthreads();
    if (tid < 64) {
        unsigned nl = sm.c.lcnt[tid];
        if (nl > (unsigned)LCAP) nl = (unsigned)LCAP;
        if (nl) {
            const int row = row0 + tid;
            unsigned base = atomicAdd(&cnt[row], nl);
            for (unsigned i = 0; i < nl; ++i) {
                unsigned pp = base + i;
                if (pp < (unsigned)CAP) candcol[(size_t)row*CAP + pp] = (int)sm.c.lcol[tid][i];
            }
        }
    }
}

// ---------------- Kernel 3: merged rescore+fixup per row ----------------
// strict-count guard computed HERE from exact fp32 dots (ballot+popc): >=TOPK candidates
// with exact dot >= ts = tf + 2D beats every uncollected column (bf16 < tf => exact < tf + D).
__global__ __launch_bounds__(64) void final_kernel(
    const unsigned* __restrict__ cnt, const int* __restrict__ candcol,
    const float* __restrict__ xf, const float* __restrict__ WvT,
    const float* __restrict__ bv, const float* __restrict__ qv, float* __restrict__ out,
    const float* __restrict__ gw2s, const float* __restrict__ nrm1, const float* __restrict__ nrm2)
{
    const int row = blockIdx.x;
    const unsigned n_all = cnt[row];
    const int l = threadIdx.x;
    const float4* xp = (const float4*)(xf + (size_t)row*128);
    float wk[TOPK]; int ik[TOPK];
    bool done = false;

    if (n_all <= (unsigned)CAP) {
        // ---- rescore path: exact fp32 over <=CAP candidates, skip empty slot-groups ----
        const int ng = ((int)n_all + 63) >> 6;
        int c[3]; float vv[3], dd[3];
        #pragma unroll
        for (int s = 0; s < 3; ++s) {
            c[s] = 0x7fffffff; vv[s] = -1e38f; dd[s] = -1e38f;
            if (s < ng) {
                bool ok = (l + s*64 < (int)n_all);
                int cc2 = ok ? candcol[(size_t)row*CAP + l + s*64] : 0;
                const float4* wp = (const float4*)(WvT + (size_t)cc2*128);
                float s0 = 0.f, s1 = 0.f, s2 = 0.f, s3 = 0.f;
                #pragma unroll
                for (int j = 0; j < 32; ++j) {
                    float4 x4 = xp[j], w4 = wp[j];
                    s0 = fmaf(x4.x, w4.x, s0); s1 = fmaf(x4.y, w4.y, s1);
                    s2 = fmaf(x4.z, w4.z, s2); s3 = fmaf(x4.w, w4.w, s3);
                }
                float dot = (s0 + s1) + (s2 + s3);
                if (ok) { dd[s] = dot; vv[s] = dot + bv[cc2]; c[s] = cc2; }
            }
        }
        float sw = sqrtf(gw2_sum(gw2s) * (1.f / (128.f * (float)VDIM)));
        float ts = ALPHA * sw * sqrtf(nrm2[row]) + DELTA_C * nrm1[row];
        int nstr = 0;
        #pragma unroll
        for (int s = 0; s < 3; ++s) nstr += (int)__popcll(__ballot(dd[s] >= ts));
        if (nstr >= TOPK) {
            #pragma unroll
            for (int k = 0; k < TOPK; ++k) {
                float mv = vv[0]; int mi = c[0];
                if (tk_better(vv[1], c[1], mv, mi)) { mv = vv[1]; mi = c[1]; }
                if (tk_better(vv[2], c[2], mv, mi)) { mv = vv[2]; mi = c[2]; }
                #pragma unroll
                for (int m = 1; m < 64; m <<= 1) {
                    float ov = __shfl_xor(mv, m);
                    int oi = __shfl_xor(mi, m);
                    if (tk_better(ov, oi, mv, mi)) { mv = ov; mi = oi; }
                }
                wk[k] = mv; ik[k] = mi;
                #pragma unroll
                for (int s = 0; s < 3; ++s) if (c[s] == mi) vv[s] = -1e38f;   // cols unique per row
            }
            done = true;
        }
    }
    if (!done) {
        // ---- fixup path: exact full scan (guard failed; ~never) ----
        float tv[TOPK]; int ti[TOPK];
        #pragma unroll
        for (int k = 0; k < TOPK; ++k) { tv[k] = -1e38f; ti[k] = 0x7fffffff; }
        for (int c2 = l; c2 < VDIM; c2 += 64) {
            const float4* wp = (const float4*)(WvT + (size_t)c2*128);
            float s0 = 0.f, s1 = 0.f, s2 = 0.f, s3 = 0.f;
            #pragma unroll
            for (int j = 0; j < 32; ++j) {
                float4 x4 = xp[j], w4 = wp[j];
                s0 = fmaf(x4.x, w4.x, s0); s1 = fmaf(x4.y, w4.y, s1);
                s2 = fmaf(x4.z, w4.z, s2); s3 = fmaf(x4.w, w4.w, s3);
            }
            tk_insertT<TOPK>(((s0 + s1) + (s2 + s3)) + bv[c2], c2, tv, ti);
        }
        int p = 0;
        for (int k = 0; k < TOPK; ++k) {
            float hv = -1e38f; int hc = 0x7fffffff;
            #pragma unroll
            for (int q = 0; q < TOPK; ++q) if (q == p) { hv = tv[q]; hc = ti[q]; }
            float mv = hv; int mi = hc;
            #pragma unroll
            for (int m = 1; m < 64; m <<= 1) {
                float ov = __shfl_xor(mv, m);
                int oi = __shfl_xor(mi, m);
                if (tk_better(ov, oi, mv, mi)) { mv = ov; mi = oi; }
            }
            wk[k] = mv; ik[k] = mi;
            if (hc == mi) ++p;
        }
    }

    float m0 = wk[0];
    float tot = 0.f;
    #pragma unroll
    for (int k = 0; k < TOPK; ++k) { wk[k] = expf(wk[k] - m0); tot += wk[k]; }
    float it = 1.f / tot;
    #pragma unroll
    for (int e = 0; e < 4; ++e) {
        int ei = l + e*64;
        float acc = 0.f;
        #pragma unroll
        for (int k = 0; k < TOPK; ++k) acc = fmaf(wk[k], qv[(size_t)ik[k]*256 + ei], acc);
        out[(size_t)row*256 + ei] = acc * it;
    }
}

// ================= OLD (fallback) path: fp32 VALU GEMM + fused top-10 =================
__global__ __launch_bounds__(256, 2) void logits_topk_kernel(
    const float* __restrict__ xf, const float* __restrict__ Wv,
    const float* __restrict__ bv, float2* __restrict__ cand)
{
    __shared__ __align__(16) float xsT[128*36];
    __shared__ __align__(16) float lt[32*260];
    const int chunk = blockIdx.x;
    const int row0  = blockIdx.y * BM;
    const int tid   = threadIdx.x;
    #pragma unroll
    for (int i = 0; i < 16; ++i) {
        int idx = i*256 + tid;
        int rr = idx >> 7, k = idx & 127;
        xsT[k*36 + rr] = xf[(row0 + rr)*128 + k];
    }
    __syncthreads();
    const int ri = tid >> 6;
    const int ci = tid & 63;
    const int srow = tid & 31;
    const int ssub = tid >> 5;
    const int cbase = chunk * TV;
    float tv[TOPK]; int tix[TOPK];
    #pragma unroll
    for (int k = 0; k < TOPK; ++k) { tv[k] = -1e38f; tix[k] = 0x7fffffff; }
    for (int cs = 0; cs < TV; cs += 256) {
        int c[4], cl[4];
        #pragma unroll
        for (int q = 0; q < 4; ++q) {
            c[q]  = cbase + cs + q*64 + ci;
            cl[q] = c[q] < VDIM ? c[q] : VDIM-1;
        }
        float acc[8][4];
        #pragma unroll
        for (int r = 0; r < 8; ++r)
            #pragma unroll
            for (int q = 0; q < 4; ++q) acc[r][q] = 0.f;
        const float* xp = xsT + ri*8;
        #pragma unroll 2
        for (int k = 0; k < 128; ++k) {
            const float* wr = Wv + (size_t)k * VDIM;
            float w0 = wr[cl[0]], w1 = wr[cl[1]], w2 = wr[cl[2]], w3 = wr[cl[3]];
            float4 xa = *(const float4*)(xp + k*36);
            float4 xb2 = *(const float4*)(xp + k*36 + 4);
            float xr[8] = {xa.x, xa.y, xa.z, xa.w, xb2.x, xb2.y, xb2.z, xb2.w};
            #pragma unroll
            for (int r = 0; r < 8; ++r) {
                acc[r][0] = fmaf(xr[r], w0, acc[r][0]);
                acc[r][1] = fmaf(xr[r], w1, acc[r][1]);
                acc[r][2] = fmaf(xr[r], w2, acc[r][2]);
                acc[r][3] = fmaf(xr[r], w3, acc[r][3]);
            }
        }
        #pragma unroll
        for (int q = 0; q < 4; ++q) {
            float bq = bv[cl[q]];
            bool valid = c[q] < VDIM;
            #pragma unroll
            for (int r = 0; r < 8; ++r)
                acc[r][q] = valid ? (acc[r][q] + bq) : -1e30f;
        }
        #pragma unroll
        for (int r = 0; r < 8; ++r) {
            float* lrow = lt + (ri*8 + r)*260;
            #pragma unroll
            for (int q = 0; q < 4; ++q) lrow[q*64 + ci] = acc[r][q];
        }
        __syncthreads();
        const float* srp = lt + srow*260 + ssub*32;
        #pragma unroll
        for (int j = 0; j < 32; j += 4) {
            float4 v4 = *(const float4*)(srp + j);
            int cc = cbase + cs + ssub*32 + j;
            tk_insertT<TOPK>(v4.x, cc+0, tv, tix);
            tk_insertT<TOPK>(v4.y, cc+1, tv, tix);
            tk_insertT<TOPK>(v4.z, cc+2, tv, tix);
            tk_insertT<TOPK>(v4.w, cc+3, tv, tix);
        }
        __syncthreads();
    }
    float* cbuf = lt;
    {
        float* myb = cbuf + (srow*8 + ssub)*TOPK*2;
        #pragma unroll
        for (int k = 0; k < TOPK; ++k) { myb[2*k] = tv[k]; myb[2*k+1] = __int_as_float(tix[k]); }
    }
    __syncthreads();
    if (tid < BM) {
        float mv[TOPK]; int mi[TOPK];
        #pragma unroll
        for (int k = 0; k < TOPK; ++k) { mv[k] = -1e38f; mi[k] = 0x7fffffff; }
        for (int s = 0; s < 8; ++s) {
            const float* cb = cbuf + (tid*8 + s)*TOPK*2;
            for (int k = 0; k < TOPK; ++k) {
                float v = cb[2*k]; int ix = __float_as_int(cb[2*k+1]);
                if (!tk_better(v, ix, mv[TOPK-1], mi[TOPK-1])) break;
                tk_insertT<TOPK>(v, ix, mv, mi);
            }
        }
        float2* outp = cand + ((size_t)(row0 + tid)*NC + chunk)*TOPK;
        #pragma unroll
        for (int k = 0; k < TOPK; ++k) outp[k] = make_float2(mv[k], __int_as_float(mi[k]));
    }
}

__global__ __launch_bounds__(64) void finalize_kernel(
    const float2* __restrict__ cand, const float* __restrict__ qv, float* __restrict__ out)
{
    const int row = blockIdx.x;
    __shared__ float wk[TOPK];
    __shared__ int   ik[TOPK];
    __shared__ float invtot;
    if (threadIdx.x == 0) {
        float mv[TOPK]; int mi[TOPK];
        #pragma unroll
        for (int k = 0; k < TOPK; ++k) { mv[k] = -1e38f; mi[k] = 0x7fffffff; }
        for (int ch = 0; ch < NC; ++ch) {
            const float2* cp = cand + ((size_t)row*NC + ch)*TOPK;
            for (int k = 0; k < TOPK; ++k) {
                float2 cv = cp[k];
                int ix = __float_as_int(cv.y);
                if (!tk_better(cv.x, ix, mv[TOPK-1], mi[TOPK-1])) break;
                tk_insertT<TOPK>(cv.x, ix, mv, mi);
            }
        }
        float m = mv[0];
        float t = 0.f;
        #pragma unroll
        for (int k = 0; k < TOPK; ++k) { float w = expf(mv[k] - m); wk[k] = w; ik[k] = mi[k]; t += w; }
        invtot = 1.f / t;
    }
    __syncthreads();
    const int l = threadIdx.x;
    float it = invtot;
    #pragma unroll
    for (int e = 0; e < 4; ++e) {
        int ei = l + e*64;
        float s = 0.f;
        #pragma unroll
        for (int k = 0; k < TOPK; ++k) s = fmaf(wk[k], qv[(size_t)ik[k]*256 + ei], s);
        out[(size_t)row*256 + ei] = s * it;
    }
}

extern "C" void kernel_launch(void* const* d_in, const int* in_sizes, int n_in,
                              void* d_out, int out_size, void* d_ws, size_t ws_size,
                              hipStream_t stream)
{
    const float* psi = (const float*)d_in[0];
    const float* qv  = (const float*)d_in[1];
    const float* W0  = (const float*)d_in[2];
    const float* b0  = (const float*)d_in[3];
    const float* g0  = (const float*)d_in[4];
    const float* be0 = (const float*)d_in[5];
    const float* W1  = (const float*)d_in[6];
    const float* b1  = (const float*)d_in[7];
    const float* g1  = (const float*)d_in[8];
    const float* be1 = (const float*)d_in[9];
    const float* W2  = (const float*)d_in[10];
    const float* b2  = (const float*)d_in[11];
    const float* g2  = (const float*)d_in[12];
    const float* be2 = (const float*)d_in[13];
    const float* Wv  = (const float*)d_in[14];
    const float* bv  = (const float*)d_in[15];
    float* out = (float*)d_out;

    auto al = [](size_t x) { return (x + 255) & ~(size_t)255; };
    const size_t o_xf   = 0;
    const size_t o_xb   = al(o_xf + (size_t)NROWS*128*4);
    const size_t o_wvt  = al(o_xb + (size_t)NROWS*128*2);
    const size_t o_wvtb = al(o_wvt + (size_t)VDIM*128*4);
    const size_t o_nrm1 = al(o_wvtb + (size_t)PADV*128*2);
    const size_t o_nrm2 = al(o_nrm1 + (size_t)NROWS*4);
    const size_t o_gw2  = al(o_nrm2 + (size_t)NROWS*4);
    const size_t o_cnt  = al(o_gw2 + 1024);      // 8 cacheline-spaced slots
    const size_t o_cand = al(o_cnt + (size_t)NROWS*4);
    const size_t need   = al(o_cand + (size_t)NROWS*CAP*4);

    if (ws_size >= need) {
        float*    xf   = (float*)((char*)d_ws + o_xf);
        __bf16*   xb   = (__bf16*)((char*)d_ws + o_xb);
        float*    WvT  = (float*)((char*)d_ws + o_wvt);
        __bf16*   WvTb = (__bf16*)((char*)d_ws + o_wvtb);
        float*    nrm1 = (float*)((char*)d_ws + o_nrm1);
        float*    nrm2 = (float*)((char*)d_ws + o_nrm2);
        float*    gw2s = (float*)((char*)d_ws + o_gw2);
        unsigned* cnt  = (unsigned*)((char*)d_ws + o_cnt);
        int*      cc   = (int*)((char*)d_ws + o_cand);
        // zero gw2 slots + cnt in one async memset (graph-capture-safe)
        hipMemsetAsync((char*)d_ws + o_gw2, 0, o_cand - o_gw2, stream);
        transpose_kernel<<<TBLK, 256, 0, stream>>>(Wv, WvTb, gw2s);
        mlp16_kernel<<<NROWS/16, 512, 0, stream>>>(
            psi, W0, b0, g0, be0, W1, b1, g1, be1, W2, b2, g2, be2,
            xf, xb, nrm1, nrm2);
        collect_kernel<<<CBLK + TBLK, 256, 0, stream>>>(xb, WvTb, gw2s, nrm2, cnt, cc, Wv, WvT);
        final_kernel<<<NROWS, 64, 0, stream>>>(cnt, cc, xf, WvT, bv, qv, out, gw2s, nrm1, nrm2);
    } else {
        // fallback: fp32 VALU path (round-1 verified)
        float* xf = (float*)d_ws;
        float2* cand = (float2*)((char*)d_ws + (size_t)NROWS*128*sizeof(float));
        mlp_kernel<<<NROWS/4, 512, 0, stream>>>(psi, W0, b0, g0, be0, W1, b1, g1, be1, W2, b2, g2, be2, xf);
        logits_topk_kernel<<<dim3(NC, NROWS/BM), 256, 0, stream>>>(xf, Wv, bv, cand);
        finalize_kernel<<<NROWS, 64, 0, stream>>>(cand, qv, out);
    }
}